// Round 5
// baseline (1630.053 us; speedup 1.0000x reference)
//
#include <hip/hip_runtime.h>

typedef unsigned int u32;
typedef unsigned short u16;
typedef unsigned char u8;

typedef __bf16 bf16_t;
typedef bf16_t bf16x8 __attribute__((ext_vector_type(8)));
typedef float f32x4 __attribute__((ext_vector_type(4)));

#define NROW 8192
#define HID 512
#define DIN 256
#define LDQ 1536   // row stride of fused qkv buffer
#define NSPLIT 4
#define KVCH (NROW / NSPLIT)   // 2048
#define KVB 32                 // kv tile

__device__ __forceinline__ u16 f2b(float f) {
    u32 u = __float_as_uint(f);
    u32 r = (u + 0x7fffu + ((u >> 16) & 1u)) >> 16;
    return (u16)r;
}
__device__ __forceinline__ float b2f(u16 h) {
    return __uint_as_float(((u32)h) << 16);
}
__device__ __forceinline__ f32x4 zero4() {
    f32x4 z = {0.f, 0.f, 0.f, 0.f};
    return z;
}
__device__ __forceinline__ void gll16(const void* g, void* l) {
    __builtin_amdgcn_global_load_lds(
        (const __attribute__((address_space(1))) unsigned int*)g,
        (__attribute__((address_space(3))) unsigned int*)l, 16, 0, 0);
}

// ---------------- adj dtype sniffing (wave-parallel) ----------------
__global__ void sniff_adj(const u32* __restrict__ adj, int* __restrict__ mode) {
    int lane = threadIdx.x & 63;
    int all01 = 1, allf32 = 1, allbf = 1;
    for (int i = lane; i < 1024; i += 64) {
        u32 w = adj[i];
        if (w > 1u) all01 = 0;
        if (w != 0u && w != 0x3f800000u) allf32 = 0;
    }
    const u16* h = (const u16*)adj;
    for (int i = lane; i < 2048; i += 64) {
        u16 v = h[i];
        if (v != 0 && v != 0x3f80u) allbf = 0;
    }
    all01 = __all(all01);
    allf32 = __all(allf32);
    allbf = __all(allbf);
    if (lane == 0) mode[0] = all01 ? 0 : (allf32 ? 1 : (allbf ? 2 : 3));
}

__global__ __launch_bounds__(256) void build_bits(const void* __restrict__ adj,
                                                  const int* __restrict__ mode,
                                                  u32* __restrict__ bits) {
    int row = blockIdx.x;
    int t = threadIdx.x;
    int lane = t & 63, wv = t >> 6;
    int md = *mode;
    for (int c0 = 0; c0 < NROW; c0 += 256) {
        int c = c0 + t;
        size_t idx = (size_t)row * NROW + c;
        bool nz;
        if (md == 0)      nz = ((const u32*)adj)[idx] != 0u;
        else if (md == 1) nz = ((const float*)adj)[idx] != 0.f;
        else if (md == 2) nz = ((const u16*)adj)[idx] != 0;
        else              nz = ((const u8*)adj)[idx] != 0;
        unsigned long long bm = __ballot(nz);
        if (lane == 0) {
            int w = row * 256 + (c0 >> 5) + wv * 2;
            bits[w] = (u32)bm;
            bits[w + 1] = (u32)(bm >> 32);
        }
    }
}

// ---------------- conversions ----------------
__global__ __launch_bounds__(256) void convert_f32_bf16(const float* __restrict__ in,
                                                        u16* __restrict__ out, int n) {
    int i = blockIdx.x * 256 + threadIdx.x;
    if (i < n) out[i] = f2b(in[i]);
}

// W [R][C] f32 -> Wt [C][R] bf16
__global__ __launch_bounds__(256) void transpose_wt(const float* __restrict__ W,
                                                    u16* __restrict__ out, int R, int C) {
    __shared__ u16 tile[64][65];
    int c0 = blockIdx.x * 64, r0 = blockIdx.y * 64;
    int t = threadIdx.x;
#pragma unroll
    for (int i = 0; i < 16; i++) {
        int idx = t + i * 256;
        int rr = idx >> 6, cc = idx & 63;
        tile[rr][cc] = f2b(W[(size_t)(r0 + rr) * C + c0 + cc]);
    }
    __syncthreads();
#pragma unroll
    for (int i = 0; i < 16; i++) {
        int idx = t + i * 256;
        int rr = idx >> 6, cc = idx & 63;
        out[(size_t)(c0 + rr) * R + r0 + cc] = tile[cc][rr];
    }
}

__global__ void concat_bias(const float* __restrict__ bq, const float* __restrict__ bk,
                            const float* __restrict__ bv, float* __restrict__ out) {
    int i = blockIdx.x * 256 + threadIdx.x;
    if (i >= 1536) return;
    out[i] = i < 512 ? bq[i] : (i < 1024 ? bk[i - 512] : bv[i - 1024]);
}

// V (rows of QKV, stride ldv) -> tiled VT: out[(kv>>5)*(HID*32) + col*32 + (kv&31)]
__global__ __launch_bounds__(256) void transpose_v_tiled(const u16* __restrict__ in, int ldv,
                                                         u16* __restrict__ out) {
    __shared__ u16 tl[64][72];
    int c0 = blockIdx.x * 64;   // col block (HID)
    int r0 = blockIdx.y * 64;   // kv block (NROW)
    int t = threadIdx.x;
#pragma unroll
    for (int i = 0; i < 2; i++) {
        int idx = t + i * 256;          // 0..511
        int rr = idx >> 3, ck = idx & 7;
        bf16x8 v = *(const bf16x8*)(in + (size_t)(r0 + rr) * ldv + c0 + ck * 8);
#pragma unroll
        for (int j = 0; j < 8; j++) tl[ck * 8 + j][rr] = ((u16*)&v)[j];
    }
    __syncthreads();
#pragma unroll
    for (int i = 0; i < 2; i++) {
        int idx = t + i * 256;
        int col = idx >> 3, ch = idx & 7;
        int kv = ch * 8;
        bf16x8 v;
#pragma unroll
        for (int j = 0; j < 8; j++) ((u16*)&v)[j] = tl[col][kv + j];
        *(bf16x8*)(out + (size_t)((r0 + kv) >> 5) * (HID * 32) +
                   (size_t)(c0 + col) * 32 + (kv & 31)) = v;
    }
}

// ---------------- GEMM 128x64, BK=64, LDS dbuf, 3 blocks/CU ----------------
// C[M,ldo] = A[M,K](lda) @ Bt[N,K]^T + bias; wave w owns rows w*32..w*32+31
__global__ __launch_bounds__(256, 3) void gemm_k(const u16* __restrict__ A, int lda,
                                                 const u16* __restrict__ Bt,
                                                 const float* __restrict__ bias,
                                                 float* __restrict__ outF,
                                                 u16* __restrict__ outH, int ldo,
                                                 int relu, int K) {
    __shared__ u16 Ald[2][8192];   // 128 x 64
    __shared__ u16 Bld[2][4096];   // 64 x 64
    int t = threadIdx.x;
    int lane = t & 63, wave = t >> 6;
    int l15 = lane & 15, lg = lane >> 4;
    int row0 = blockIdx.y * 128, col0 = blockIdx.x * 64;

    auto stage = [&](int buf, int kk) {
#pragma unroll
        for (int p = 0; p < 4; p++) {
            int idx = p * 256 + t;
            int row = idx >> 3, c = idx & 7;
            gll16(A + (size_t)(row0 + row) * lda + kk + ((c ^ (row & 7)) * 8),
                  &Ald[buf][idx * 8]);
        }
#pragma unroll
        for (int p = 0; p < 2; p++) {
            int idx = p * 256 + t;
            int row = idx >> 3, c = idx & 7;
            gll16(Bt + (size_t)(col0 + row) * K + kk + ((c ^ (row & 7)) * 8),
                  &Bld[buf][idx * 8]);
        }
    };

    f32x4 acc[2][4];
#pragma unroll
    for (int i = 0; i < 2; i++)
#pragma unroll
        for (int j = 0; j < 4; j++) acc[i][j] = zero4();

    stage(0, 0);
    asm volatile("s_waitcnt vmcnt(0)" ::: "memory");
    __syncthreads();

    int nk = K >> 6;
    for (int kt = 0; kt < nk; kt++) {
        int buf = kt & 1;
        if (kt + 1 < nk) stage(buf ^ 1, (kt + 1) * 64);
#pragma unroll
        for (int ks = 0; ks < 2; ks++) {
            bf16x8 af[2], bfr[4];
#pragma unroll
            for (int i = 0; i < 2; i++) {
                int row = wave * 32 + i * 16 + l15;
                af[i] = *(const bf16x8*)&Ald[buf][row * 64 + (((ks * 4 + lg) ^ (row & 7)) * 8)];
            }
#pragma unroll
            for (int j = 0; j < 4; j++) {
                int row = j * 16 + l15;
                bfr[j] = *(const bf16x8*)&Bld[buf][row * 64 + (((ks * 4 + lg) ^ (row & 7)) * 8)];
            }
            __builtin_amdgcn_s_setprio(1);
#pragma unroll
            for (int i = 0; i < 2; i++)
#pragma unroll
                for (int j = 0; j < 4; j++)
                    acc[i][j] = __builtin_amdgcn_mfma_f32_16x16x32_bf16(af[i], bfr[j],
                                                                       acc[i][j], 0, 0, 0);
            __builtin_amdgcn_s_setprio(0);
        }
        asm volatile("s_waitcnt vmcnt(0)" ::: "memory");
        __syncthreads();
    }
#pragma unroll
    for (int j = 0; j < 4; j++) {
        int col = col0 + j * 16 + l15;
        float bv = bias[col];
#pragma unroll
        for (int i = 0; i < 2; i++) {
#pragma unroll
            for (int r = 0; r < 4; r++) {
                int row = row0 + wave * 32 + i * 16 + lg * 4 + r;
                float v = acc[i][j][r] + bv;
                if (relu) v = fmaxf(v, 0.f);
                size_t o = (size_t)row * ldo + col;
                if (outF) outF[o] = v;
                if (outH) outH[o] = f2b(v);
            }
        }
    }
}

// ---------------- split-KV flash attention v5 ----------------
// 256 blocks = 64 qb x 4 splits; 4 waves x 32 q rows = 128 rows/block; KVB=32.
// K AND V LDS-staged (dbuf, conflict-free linear layouts via pre-swizzled
// global_load_lds source). Q resident in registers (128 VGPR), acc in AGPRs.
__global__ __launch_bounds__(256, 1) void attn_kernel(const u16* __restrict__ QKV,
                                                      const u16* __restrict__ VTt,
                                                      const u32* __restrict__ bits,
                                                      u16* __restrict__ Opart,
                                                      float* __restrict__ Mpart,
                                                      float* __restrict__ Lpart) {
    extern __shared__ char smem[];
    u16* Klds = (u16*)smem;                               // 2 x 32KB
    u16* Vlds = (u16*)(smem + 65536);                     // 2 x 32KB
    int lane = threadIdx.x & 63, wave = threadIdx.x >> 6;
    u16* myp = (u16*)(smem + 131072) + wave * 1024;       // per-wave 2KB P (32x32)
    int l15 = lane & 15, lg = lane >> 4;
    int s = blockIdx.x & 3;
    int qb = blockIdx.x >> 2;
    int qbase = qb * 128 + wave * 32;
    const u16* Kg = QKV + 512;

    // Q preload: 2 row-groups x 16 A-frags (128 VGPR)
    bf16x8 qf[2][16];
#pragma unroll
    for (int g = 0; g < 2; g++) {
        const u16* qp = QKV + (size_t)(qbase + g * 16 + l15) * LDQ + lg * 8;
#pragma unroll
        for (int ks = 0; ks < 16; ks++) qf[g][ks] = *(const bf16x8*)(qp + ks * 32);
    }

    f32x4 acc[2][32];
#pragma unroll
    for (int g = 0; g < 2; g++)
#pragma unroll
        for (int i = 0; i < 32; i++) acc[g][i] = zero4();
    float m[2][4], lsum[2][4];
#pragma unroll
    for (int g = 0; g < 2; g++)
#pragma unroll
        for (int r = 0; r < 4; r++) { m[g][r] = -1e30f; lsum[g][r] = 0.f; }
    const float scale = 0.04419417382415922f;  // 1/sqrt(512)
    int kvbeg = s * KVCH;

    // stage K (32KB) + V (32KB): 32 segs of 1KB each; 4 waves x 8 segs
    auto STAGE = [&](int buf, int kv0) {
        const u16* vb = VTt + (size_t)(kv0 >> 5) * (HID * 32);
#pragma unroll
        for (int i = 0; i < 8; i++) {
            int seg = wave * 8 + i;
            gll16(Kg + (size_t)(kv0 + (seg & 1) * 16 + l15) * LDQ +
                      (seg >> 1) * 32 + lg * 8,
                  Klds + buf * 16384 + seg * 512 + lane * 8);
            gll16(vb + (size_t)(seg * 16 + l15) * 32 + lg * 8,
                  Vlds + buf * 16384 + seg * 512 + lane * 8);
        }
    };

    STAGE(0, kvbeg);
    asm volatile("s_waitcnt vmcnt(0)" ::: "memory");
    __syncthreads();

    for (int t = 0; t < KVCH / KVB; ++t) {
        int kv0 = kvbeg + t * KVB;
        int buf = t & 1;
        if (t + 1 < KVCH / KVB) STAGE(buf ^ 1, kv0 + KVB);
        const u16* kb = Klds + buf * 16384;

        // ---- S = Q(32x512) @ K^T(512x32): 4 independent MFMA chains ----
        f32x4 sf[2][2];
        sf[0][0] = zero4(); sf[0][1] = zero4();
        sf[1][0] = zero4(); sf[1][1] = zero4();
        __builtin_amdgcn_s_setprio(1);
#pragma unroll
        for (int ks = 0; ks < 16; ks++) {
            bf16x8 b0 = *(const bf16x8*)(kb + ks * 1024 + lane * 8);
            bf16x8 b1 = *(const bf16x8*)(kb + ks * 1024 + 512 + lane * 8);
            sf[0][0] = __builtin_amdgcn_mfma_f32_16x16x32_bf16(qf[0][ks], b0, sf[0][0], 0, 0, 0);
            sf[0][1] = __builtin_amdgcn_mfma_f32_16x16x32_bf16(qf[0][ks], b1, sf[0][1], 0, 0, 0);
            sf[1][0] = __builtin_amdgcn_mfma_f32_16x16x32_bf16(qf[1][ks], b0, sf[1][0], 0, 0, 0);
            sf[1][1] = __builtin_amdgcn_mfma_f32_16x16x32_bf16(qf[1][ks], b1, sf[1][1], 0, 0, 0);
        }
        __builtin_amdgcn_s_setprio(0);

        // ---- mask + online softmax (defer-max THR=8), both row-groups ----
        float pvv[2][2][4];
        float mx[2][4];
        bool need = false;
#pragma unroll
        for (int g = 0; g < 2; g++) {
            u32 w0[4];
#pragma unroll
            for (int r = 0; r < 4; r++)
                w0[r] = bits[(size_t)(qbase + g * 16 + lg * 4 + r) * 256 + (kv0 >> 5)];
#pragma unroll
            for (int r = 0; r < 4; r++) mx[g][r] = -1e30f;
#pragma unroll
            for (int f = 0; f < 2; f++) {
                int c = f * 16 + l15;
#pragma unroll
                for (int r = 0; r < 4; r++) {
                    bool bit = (w0[r] >> c) & 1u;
                    float sv = bit ? sf[g][f][r] * scale : -1e30f;
                    pvv[g][f][r] = sv;
                    mx[g][r] = fmaxf(mx[g][r], sv);
                }
            }
#pragma unroll
            for (int r = 0; r < 4; r++) {
#pragma unroll
                for (int off = 8; off; off >>= 1)
                    mx[g][r] = fmaxf(mx[g][r], __shfl_xor(mx[g][r], off, 64));
                need |= (mx[g][r] > m[g][r] + 8.0f);
            }
        }
        if (__any(need ? 1 : 0)) {
#pragma unroll
            for (int g = 0; g < 2; g++) {
                float csc[4];
#pragma unroll
                for (int r = 0; r < 4; r++) {
                    float mn = fmaxf(m[g][r], mx[g][r]);
                    csc[r] = __expf(m[g][r] - mn);
                    m[g][r] = mn;
                    lsum[g][r] *= csc[r];
                }
#pragma unroll
                for (int i = 0; i < 32; i++) {
                    f32x4 a = acc[g][i];
                    a[0] *= csc[0]; a[1] *= csc[1]; a[2] *= csc[2]; a[3] *= csc[3];
                    acc[g][i] = a;
                }
            }
        }
#pragma unroll
        for (int g = 0; g < 2; g++) {
#pragma unroll
            for (int f = 0; f < 2; f++)
#pragma unroll
                for (int r = 0; r < 4; r++)
                    pvv[g][f][r] = (pvv[g][f][r] < -1e29f) ? 0.f : __expf(pvv[g][f][r] - m[g][r]);
#pragma unroll
            for (int r = 0; r < 4; r++) {
                float rs = pvv[g][0][r] + pvv[g][1][r];
#pragma unroll
                for (int off = 8; off; off >>= 1) rs += __shfl_xor(rs, off, 64);
                lsum[g][r] += rs;
            }
        }

        // ---- P (D-layout) -> per-wave LDS (linear layout) -> A-frags ----
#pragma unroll
        for (int g = 0; g < 2; g++)
#pragma unroll
            for (int f = 0; f < 2; f++)
#pragma unroll
                for (int r = 0; r < 4; r++)
                    myp[g * 512 + (f * 2 + (l15 >> 3)) * 128 + (lg * 4 + r) * 8 + (l15 & 7)] =
                        f2b(pvv[g][f][r]);
        asm volatile("s_waitcnt lgkmcnt(0)" ::: "memory");
        __builtin_amdgcn_sched_barrier(0);
        bf16x8 pa0 = *(const bf16x8*)(myp + lane * 8);
        bf16x8 pa1 = *(const bf16x8*)(myp + 512 + lane * 8);

        // ---- O += P(32x32) @ V(32x512): V-frag from LDS feeds both groups ----
        const u16* vb = Vlds + buf * 16384;
        __builtin_amdgcn_s_setprio(1);
#pragma unroll
        for (int cf = 0; cf < 32; ++cf) {
            bf16x8 v = *(const bf16x8*)(vb + cf * 512 + lane * 8);
            acc[0][cf] = __builtin_amdgcn_mfma_f32_16x16x32_bf16(pa0, v, acc[0][cf], 0, 0, 0);
            acc[1][cf] = __builtin_amdgcn_mfma_f32_16x16x32_bf16(pa1, v, acc[1][cf], 0, 0, 0);
        }
        __builtin_amdgcn_s_setprio(0);

        asm volatile("s_waitcnt vmcnt(0)" ::: "memory");
        __syncthreads();
    }

    // ---- write partials ----
    if (l15 == 0) {
#pragma unroll
        for (int g = 0; g < 2; g++)
#pragma unroll
            for (int r = 0; r < 4; r++) {
                size_t o = (size_t)s * NROW + qbase + g * 16 + lg * 4 + r;
                Mpart[o] = m[g][r];
                Lpart[o] = lsum[g][r];
            }
    }
#pragma unroll
    for (int g = 0; g < 2; g++)
#pragma unroll
        for (int cf = 0; cf < 32; cf++) {
            int col = cf * 16 + l15;
#pragma unroll
            for (int r = 0; r < 4; r++) {
                size_t row = (size_t)s * NROW + qbase + g * 16 + lg * 4 + r;
                Opart[row * HID + col] = f2b(acc[g][cf][r]);
            }
        }
}

// combine 4 split partials -> O16
__global__ __launch_bounds__(256) void attn_combine(const u16* __restrict__ Opart,
                                                    const float* __restrict__ Mpart,
                                                    const float* __restrict__ Lpart,
                                                    u16* __restrict__ O16) {
    int idx = blockIdx.x * 256 + threadIdx.x;
    int row = idx >> 6;
    int c8 = (idx & 63) << 3;
    float ms[NSPLIT], M = -1e30f;
#pragma unroll
    for (int s = 0; s < NSPLIT; s++) {
        ms[s] = Mpart[(size_t)s * NROW + row];
        M = fmaxf(M, ms[s]);
    }
    float w[NSPLIT], L = 0.f;
#pragma unroll
    for (int s = 0; s < NSPLIT; s++) {
        w[s] = __expf(ms[s] - M);
        L += Lpart[(size_t)s * NROW + row] * w[s];
    }
    float inv = 1.f / L;
    float o[8];
#pragma unroll
    for (int j = 0; j < 8; j++) o[j] = 0.f;
#pragma unroll
    for (int s = 0; s < NSPLIT; s++) {
        bf16x8 p = *(const bf16x8*)(Opart + ((size_t)s * NROW + row) * HID + c8);
#pragma unroll
        for (int j = 0; j < 8; j++) o[j] += (float)p[j] * w[s];
    }
    bf16x8 res;
#pragma unroll
    for (int j = 0; j < 8; j++) {
        u16 b = f2b(o[j] * inv);
        res[j] = *(bf16_t*)&b;
    }
    *(bf16x8*)(O16 + (size_t)row * HID + c8) = res;
}

// ---------------- layernorm(a+b) ----------------
__global__ __launch_bounds__(256) void ln_add(const float* __restrict__ a,
                                              const float* __restrict__ b,
                                              const float* __restrict__ g,
                                              const float* __restrict__ be,
                                              float* __restrict__ outF,
                                              u16* __restrict__ outH) {
    int row = blockIdx.x, t = threadIdx.x;
    const float* ar = a + (size_t)row * HID;
    const float* br = b + (size_t)row * HID;
    float x0 = ar[t] + br[t];
    float x1 = ar[t + 256] + br[t + 256];
    float s = x0 + x1, s2 = x0 * x0 + x1 * x1;
#pragma unroll
    for (int off = 32; off; off >>= 1) {
        s += __shfl_xor(s, off, 64);
        s2 += __shfl_xor(s2, off, 64);
    }
    __shared__ float ls[4], ls2[4];
    int wv = t >> 6, ln = t & 63;
    if (ln == 0) { ls[wv] = s; ls2[wv] = s2; }
    __syncthreads();
    float S = ls[0] + ls[1] + ls[2] + ls[3];
    float S2 = ls2[0] + ls2[1] + ls2[2] + ls2[3];
    float mu = S * (1.f / 512.f);
    float var = S2 * (1.f / 512.f) - mu * mu;
    float inv = rsqrtf(var + 1e-5f);
    float y0 = (x0 - mu) * inv * g[t] + be[t];
    float y1 = (x1 - mu) * inv * g[t + 256] + be[t + 256];
    size_t o = (size_t)row * HID + t;
    if (outF) { outF[o] = y0; outF[o + 256] = y1; }
    if (outH) { outH[o] = f2b(y0); outH[o + 256] = f2b(y1); }
}

// ---------------- logits ----------------
__global__ __launch_bounds__(256) void logits_k(const u16* __restrict__ hfin,
                                                const float* __restrict__ Ws,
                                                const float* __restrict__ bs,
                                                float* __restrict__ out) {
    int row = blockIdx.x * 4 + (threadIdx.x >> 6);
    int lane = threadIdx.x & 63;
    const u16* hp = hfin + (size_t)row * HID + lane * 8;
    float sum = 0.f;
#pragma unroll
    for (int j = 0; j < 8; j++) sum += b2f(hp[j]) * Ws[lane * 8 + j];
#pragma unroll
    for (int off = 32; off; off >>= 1) sum += __shfl_xor(sum, off, 64);
    if (lane == 0) out[row] = sum + bs[0];
}

// ---------------- host launcher ----------------
extern "C" void kernel_launch(void* const* d_in, const int* in_sizes, int n_in,
                              void* d_out, int out_size, void* d_ws, size_t ws_size,
                              hipStream_t stream) {
    const float* x   = (const float*)d_in[0];
    const void*  adj = d_in[1];
    const float* Win = (const float*)d_in[2];
    const float* b_in= (const float*)d_in[3];
    const float* Wq  = (const float*)d_in[4];
    const float* bq  = (const float*)d_in[5];
    const float* Wk  = (const float*)d_in[6];
    const float* bk  = (const float*)d_in[7];
    const float* Wv  = (const float*)d_in[8];
    const float* bv  = (const float*)d_in[9];
    const float* Wo  = (const float*)d_in[10];
    const float* bo  = (const float*)d_in[11];
    const float* Ws  = (const float*)d_in[12];
    const float* bs  = (const float*)d_in[13];
    const float* g1  = (const float*)d_in[14];
    const float* be1 = (const float*)d_in[15];
    const float* g2  = (const float*)d_in[16];
    const float* be2 = (const float*)d_in[17];
    const float* Wf1 = (const float*)d_in[18];
    const float* bf1 = (const float*)d_in[19];
    const float* Wf2 = (const float*)d_in[20];
    const float* bf2 = (const float*)d_in[21];

    char* ws = (char*)d_ws;
    const size_t MB = 1u << 20;
    const size_t OFF_PART = 0;            // 32MB partial O (attn..combine) overlays:
    const size_t OFF_X16  = 0;            //   4MB x bf16   (dead after h-gemm)
    const size_t OFF_H16  = 4 * MB;       //   8MB h bf16   (dead after qkv-gemm)
    const size_t OFF_HN32 = 12 * MB;      //  16MB ln1 f32  (written after combine)
    const size_t OFF_HN16 = 28 * MB;      //   8MB ln1 bf16
    const size_t OFF_FF1  = 4 * MB;       //   8MB (overlays dead H16)
    const size_t OFF_HF32 = 36 * MB;      //  16MB h f32 (h-gemm .. LN1)
    const size_t OFF_QKV  = 52 * MB;      //  24MB fused qkv bf16 (dead after attn)
    const size_t OFF_OP32 = 52 * MB;      //  16MB o-proj f32 (overlays dead QKV)
    const size_t OFF_FF2  = 52 * MB;      //  16MB (overlays dead OP32)
    const size_t OFF_VT   = 76 * MB;      //   8MB tiled VT (dead after attn)
    const size_t OFF_HFIN = 76 * MB;      //   8MB final hidden (overlays dead VT)
    const size_t OFF_H2   = 84 * MB;      //   8MB attn out bf16
    const size_t OFF_BITS = 92 * MB;      //   8MB adjacency bitmask
    size_t off = 100 * MB;
    const size_t OFF_WINT = off;  off += 262144;
    const size_t OFF_QKVT = off;  off += 1572864;
    const size_t OFF_WOT  = off;  off += 524288;
    const size_t OFF_WF1T = off;  off += 524288;
    const size_t OFF_WF2T = off;  off += 524288;
    const size_t OFF_BQKV = off;  off += 8192;
    const size_t OFF_MODE = off;  off += 4096;
    const size_t OFF_MPART= off;  off += 131072;
    const size_t OFF_LPART= off;  off += 131072;

    u16* pX16   = (u16*)(ws + OFF_X16);
    u16* pH16   = (u16*)(ws + OFF_H16);
    float* pHN32= (float*)(ws + OFF_HN32);
    u16* pHN16  = (u16*)(ws + OFF_HN16);
    u16* pFF1   = (u16*)(ws + OFF_FF1);
    float* pHF32= (float*)(ws + OFF_HF32);
    u16* pQKV   = (u16*)(ws + OFF_QKV);
    float* pOP32= (float*)(ws + OFF_OP32);
    float* pFF2 = (float*)(ws + OFF_FF2);
    u16* pVT    = (u16*)(ws + OFF_VT);
    u16* pHFIN  = (u16*)(ws + OFF_HFIN);
    u16* pH2    = (u16*)(ws + OFF_H2);
    u32* pBits  = (u32*)(ws + OFF_BITS);
    u16* pPart  = (u16*)(ws + OFF_PART);
    u16* pWinT  = (u16*)(ws + OFF_WINT);
    u16* pQKVT  = (u16*)(ws + OFF_QKVT);
    u16* pWoT   = (u16*)(ws + OFF_WOT);
    u16* pWf1T  = (u16*)(ws + OFF_WF1T);
    u16* pWf2T  = (u16*)(ws + OFF_WF2T);
    float* pBqkv= (float*)(ws + OFF_BQKV);
    int* pMode  = (int*)(ws + OFF_MODE);
    float* pMp  = (float*)(ws + OFF_MPART);
    float* pLp  = (float*)(ws + OFF_LPART);

    // adjacency bitmask
    sniff_adj<<<1, 64, 0, stream>>>((const u32*)adj, pMode);
    build_bits<<<NROW, 256, 0, stream>>>(adj, pMode, pBits);

    // conversions
    convert_f32_bf16<<<(NROW * DIN) / 256, 256, 0, stream>>>(x, pX16, NROW * DIN);
    transpose_wt<<<dim3(8, 4), 256, 0, stream>>>(Win, pWinT, DIN, HID);
    transpose_wt<<<dim3(8, 8), 256, 0, stream>>>(Wq, pQKVT, HID, HID);
    transpose_wt<<<dim3(8, 8), 256, 0, stream>>>(Wk, pQKVT + 512 * 512, HID, HID);
    transpose_wt<<<dim3(8, 8), 256, 0, stream>>>(Wv, pQKVT + 2 * 512 * 512, HID, HID);
    transpose_wt<<<dim3(8, 8), 256, 0, stream>>>(Wo, pWoT, HID, HID);
    transpose_wt<<<dim3(8, 8), 256, 0, stream>>>(Wf1, pWf1T, HID, HID);
    transpose_wt<<<dim3(8, 8), 256, 0, stream>>>(Wf2, pWf2T, HID, HID);
    concat_bias<<<6, 256, 0, stream>>>(bq, bk, bv, pBqkv);

    // h = x @ Win + b_in (f32 + bf16)
    gemm_k<<<dim3(8, 64), 256, 0, stream>>>(pX16, DIN, pWinT, b_in,
                                            pHF32, pH16, HID, 0, DIN);
    // qkv = h @ [Wq|Wk|Wv] (bf16, fused, ldo=1536)
    gemm_k<<<dim3(24, 64), 256, 0, stream>>>(pH16, HID, pQKVT, pBqkv,
                                             nullptr, pQKV, LDQ, 0, HID);
    // tiled vt
    transpose_v_tiled<<<dim3(HID / 64, NROW / 64), 256, 0, stream>>>(pQKV + 1024, LDQ, pVT);
    // attention (split-KV) + combine
    attn_kernel<<<64 * NSPLIT, 256, 139264, stream>>>(pQKV, pVT, pBits, pPart, pMp, pLp);
    attn_combine<<<NROW * HID / (256 * 8), 256, 0, stream>>>(pPart, pMp, pLp, pH2);
    // o-proj (f32)
    gemm_k<<<dim3(8, 64), 256, 0, stream>>>(pH2, HID, pWoT, bo,
                                            pOP32, nullptr, HID, 0, HID);
    // LN1
    ln_add<<<NROW, 256, 0, stream>>>(pHF32, pOP32, g1, be1, pHN32, pHN16);
    // ff1 = relu(hn @ Wf1 + bf1)
    gemm_k<<<dim3(8, 64), 256, 0, stream>>>(pHN16, HID, pWf1T, bf1,
                                            nullptr, pFF1, HID, 1, HID);
    // ff2
    gemm_k<<<dim3(8, 64), 256, 0, stream>>>(pFF1, HID, pWf2T, bf2,
                                            pFF2, nullptr, HID, 0, HID);
    // LN2 -> bf16
    ln_add<<<NROW, 256, 0, stream>>>(pHN32, pFF2, g2, be2, nullptr, pHFIN);
    // logits
    logits_k<<<NROW / 4, 256, 0, stream>>>(pHFIN, Ws, bs, (float*)d_out);
}

// Round 6
// 675.010 us; speedup vs baseline: 2.4149x; 2.4149x over previous
//
#include <hip/hip_runtime.h>

typedef unsigned int u32;
typedef unsigned short u16;
typedef unsigned char u8;

typedef __bf16 bf16_t;
typedef bf16_t bf16x8 __attribute__((ext_vector_type(8)));
typedef float f32x4 __attribute__((ext_vector_type(4)));

#define NROW 8192
#define HID 512
#define DIN 256
#define LDQ 1536   // row stride of fused qkv buffer
#define NSPLIT 4
#define KVCH (NROW / NSPLIT)   // 2048
#define KVB 32                 // kv tile

__device__ __forceinline__ u16 f2b(float f) {
    u32 u = __float_as_uint(f);
    u32 r = (u + 0x7fffu + ((u >> 16) & 1u)) >> 16;
    return (u16)r;
}
__device__ __forceinline__ float b2f(u16 h) {
    return __uint_as_float(((u32)h) << 16);
}
__device__ __forceinline__ f32x4 zero4() {
    f32x4 z = {0.f, 0.f, 0.f, 0.f};
    return z;
}
__device__ __forceinline__ void gll16(const void* g, void* l) {
    __builtin_amdgcn_global_load_lds(
        (const __attribute__((address_space(1))) unsigned int*)g,
        (__attribute__((address_space(3))) unsigned int*)l, 16, 0, 0);
}

// ---------------- adj dtype sniffing (256-thread parallel) ----------------
__global__ void sniff_adj(const u32* __restrict__ adj, int* __restrict__ mode) {
    __shared__ int f01[4], ff32[4], fbf[4];
    int t = threadIdx.x, lane = t & 63, wv = t >> 6;
    int all01 = 1, allf32 = 1, allbf = 1;
    for (int i = t; i < 1024; i += 256) {
        u32 w = adj[i];
        if (w > 1u) all01 = 0;
        if (w != 0u && w != 0x3f800000u) allf32 = 0;
    }
    const u16* h = (const u16*)adj;
    for (int i = t; i < 2048; i += 256) {
        u16 v = h[i];
        if (v != 0 && v != 0x3f80u) allbf = 0;
    }
    all01 = __all(all01);
    allf32 = __all(allf32);
    allbf = __all(allbf);
    if (lane == 0) { f01[wv] = all01; ff32[wv] = allf32; fbf[wv] = allbf; }
    __syncthreads();
    if (t == 0) {
        int a = f01[0] & f01[1] & f01[2] & f01[3];
        int b = ff32[0] & ff32[1] & ff32[2] & ff32[3];
        int c = fbf[0] & fbf[1] & fbf[2] & fbf[3];
        mode[0] = a ? 0 : (b ? 1 : (c ? 2 : 3));
    }
}

__global__ __launch_bounds__(256) void build_bits(const void* __restrict__ adj,
                                                  const int* __restrict__ mode,
                                                  u32* __restrict__ bits) {
    int row = blockIdx.x;
    int t = threadIdx.x;
    int lane = t & 63, wv = t >> 6;
    int md = *mode;
    for (int c0 = 0; c0 < NROW; c0 += 256) {
        int c = c0 + t;
        size_t idx = (size_t)row * NROW + c;
        bool nz;
        if (md == 0)      nz = ((const u32*)adj)[idx] != 0u;
        else if (md == 1) nz = ((const float*)adj)[idx] != 0.f;
        else if (md == 2) nz = ((const u16*)adj)[idx] != 0;
        else              nz = ((const u8*)adj)[idx] != 0;
        unsigned long long bm = __ballot(nz);
        if (lane == 0) {
            int w = row * 256 + (c0 >> 5) + wv * 2;
            bits[w] = (u32)bm;
            bits[w + 1] = (u32)(bm >> 32);
        }
    }
}

// ---------------- conversions ----------------
__global__ __launch_bounds__(256) void convert_f32_bf16(const float* __restrict__ in,
                                                        u16* __restrict__ out, int n) {
    int i = blockIdx.x * 256 + threadIdx.x;
    if (i < n) out[i] = f2b(in[i]);
}

// W [R][C] f32 -> Wt [C][R] bf16
__global__ __launch_bounds__(256) void transpose_wt(const float* __restrict__ W,
                                                    u16* __restrict__ out, int R, int C) {
    __shared__ u16 tile[64][65];
    int c0 = blockIdx.x * 64, r0 = blockIdx.y * 64;
    int t = threadIdx.x;
#pragma unroll
    for (int i = 0; i < 16; i++) {
        int idx = t + i * 256;
        int rr = idx >> 6, cc = idx & 63;
        tile[rr][cc] = f2b(W[(size_t)(r0 + rr) * C + c0 + cc]);
    }
    __syncthreads();
#pragma unroll
    for (int i = 0; i < 16; i++) {
        int idx = t + i * 256;
        int rr = idx >> 6, cc = idx & 63;
        out[(size_t)(c0 + rr) * R + r0 + cc] = tile[cc][rr];
    }
}

__global__ void concat_bias(const float* __restrict__ bq, const float* __restrict__ bk,
                            const float* __restrict__ bv, float* __restrict__ out) {
    int i = blockIdx.x * 256 + threadIdx.x;
    if (i >= 1536) return;
    out[i] = i < 512 ? bq[i] : (i < 1024 ? bk[i - 512] : bv[i - 1024]);
}

// V (rows of QKV, stride ldv) -> tiled VT: out[(kv>>5)*(HID*32) + col*32 + (kv&31)]
__global__ __launch_bounds__(256) void transpose_v_tiled(const u16* __restrict__ in, int ldv,
                                                         u16* __restrict__ out) {
    __shared__ u16 tl[64][72];
    int c0 = blockIdx.x * 64;   // col block (HID)
    int r0 = blockIdx.y * 64;   // kv block (NROW)
    int t = threadIdx.x;
#pragma unroll
    for (int i = 0; i < 2; i++) {
        int idx = t + i * 256;          // 0..511
        int rr = idx >> 3, ck = idx & 7;
        bf16x8 v = *(const bf16x8*)(in + (size_t)(r0 + rr) * ldv + c0 + ck * 8);
#pragma unroll
        for (int j = 0; j < 8; j++) tl[ck * 8 + j][rr] = ((u16*)&v)[j];
    }
    __syncthreads();
#pragma unroll
    for (int i = 0; i < 2; i++) {
        int idx = t + i * 256;
        int col = idx >> 3, ch = idx & 7;
        int kv = ch * 8;
        bf16x8 v;
#pragma unroll
        for (int j = 0; j < 8; j++) ((u16*)&v)[j] = tl[col][kv + j];
        *(bf16x8*)(out + (size_t)((r0 + kv) >> 5) * (HID * 32) +
                   (size_t)(c0 + col) * 32 + (kv & 31)) = v;
    }
}

// ---------------- GEMM 128x64, BK=64, LDS dbuf, 3 blocks/CU ----------------
// C[M,ldo] = A[M,K](lda) @ Bt[N,K]^T + bias (+resid); wave w owns rows w*32..+31
__global__ __launch_bounds__(256, 3) void gemm_k(const u16* __restrict__ A, int lda,
                                                 const u16* __restrict__ Bt,
                                                 const float* __restrict__ bias,
                                                 const float* __restrict__ resid,
                                                 float* __restrict__ outF,
                                                 u16* __restrict__ outH, int ldo,
                                                 int relu, int K) {
    __shared__ u16 Ald[2][8192];   // 128 x 64
    __shared__ u16 Bld[2][4096];   // 64 x 64
    int t = threadIdx.x;
    int lane = t & 63, wave = t >> 6;
    int l15 = lane & 15, lg = lane >> 4;
    int row0 = blockIdx.y * 128, col0 = blockIdx.x * 64;

    auto stage = [&](int buf, int kk) {
#pragma unroll
        for (int p = 0; p < 4; p++) {
            int idx = p * 256 + t;
            int row = idx >> 3, c = idx & 7;
            gll16(A + (size_t)(row0 + row) * lda + kk + ((c ^ (row & 7)) * 8),
                  &Ald[buf][idx * 8]);
        }
#pragma unroll
        for (int p = 0; p < 2; p++) {
            int idx = p * 256 + t;
            int row = idx >> 3, c = idx & 7;
            gll16(Bt + (size_t)(col0 + row) * K + kk + ((c ^ (row & 7)) * 8),
                  &Bld[buf][idx * 8]);
        }
    };

    f32x4 acc[2][4];
#pragma unroll
    for (int i = 0; i < 2; i++)
#pragma unroll
        for (int j = 0; j < 4; j++) acc[i][j] = zero4();

    stage(0, 0);
    asm volatile("s_waitcnt vmcnt(0)" ::: "memory");
    __syncthreads();

    int nk = K >> 6;
    for (int kt = 0; kt < nk; kt++) {
        int buf = kt & 1;
        if (kt + 1 < nk) stage(buf ^ 1, (kt + 1) * 64);
#pragma unroll
        for (int ks = 0; ks < 2; ks++) {
            bf16x8 af[2], bfr[4];
#pragma unroll
            for (int i = 0; i < 2; i++) {
                int row = wave * 32 + i * 16 + l15;
                af[i] = *(const bf16x8*)&Ald[buf][row * 64 + (((ks * 4 + lg) ^ (row & 7)) * 8)];
            }
#pragma unroll
            for (int j = 0; j < 4; j++) {
                int row = j * 16 + l15;
                bfr[j] = *(const bf16x8*)&Bld[buf][row * 64 + (((ks * 4 + lg) ^ (row & 7)) * 8)];
            }
            __builtin_amdgcn_s_setprio(1);
#pragma unroll
            for (int i = 0; i < 2; i++)
#pragma unroll
                for (int j = 0; j < 4; j++)
                    acc[i][j] = __builtin_amdgcn_mfma_f32_16x16x32_bf16(af[i], bfr[j],
                                                                       acc[i][j], 0, 0, 0);
            __builtin_amdgcn_s_setprio(0);
        }
        asm volatile("s_waitcnt vmcnt(0)" ::: "memory");
        __syncthreads();
    }
#pragma unroll
    for (int j = 0; j < 4; j++) {
        int col = col0 + j * 16 + l15;
        float bv = bias[col];
#pragma unroll
        for (int i = 0; i < 2; i++) {
#pragma unroll
            for (int r = 0; r < 4; r++) {
                int row = row0 + wave * 32 + i * 16 + lg * 4 + r;
                float v = acc[i][j][r] + bv;
                if (relu) v = fmaxf(v, 0.f);
                size_t o = (size_t)row * ldo + col;
                if (resid) v += resid[o];
                if (outF) outF[o] = v;
                if (outH) outH[o] = f2b(v);
            }
        }
    }
}

// ---------------- split-KV flash attention v6 ----------------
// 256 blocks = 64 qb x 4 splits -> exactly 1 block/CU (LDS padded to 88KB).
// 8 waves x 16 q rows = 128 rows/block; KVB=32.
// K LDS-staged (dbuf, conflict-free linear layout via pre-swizzled gll source);
// V from tiled-VT global (L1-resident 32KB tile, prefetch depth 4);
// P per-wave LDS, conflict-free linear layout. Q resident in registers.
__global__ __launch_bounds__(512, 2) void attn_kernel(const u16* __restrict__ QKV,
                                                      const u16* __restrict__ VTt,
                                                      const u32* __restrict__ bits,
                                                      u16* __restrict__ Opart,
                                                      float* __restrict__ Mpart,
                                                      float* __restrict__ Lpart) {
    extern __shared__ char smem[];
    u16* Klds = (u16*)smem;                               // 2 x 32KB
    int lane = threadIdx.x & 63, wave = threadIdx.x >> 6;
    u16* myp = (u16*)(smem + 65536) + wave * 512;         // per-wave 1KB P (16x32)
    int l15 = lane & 15, lg = lane >> 4;
    int s = blockIdx.x & 3;
    int qb = blockIdx.x >> 2;
    int qbase = qb * 128 + wave * 16;
    const u16* Kg = QKV + 512;

    // Q preload: 16 A-frags (64 VGPR)
    bf16x8 qf[16];
    {
        const u16* qp = QKV + (size_t)(qbase + l15) * LDQ + lg * 8;
#pragma unroll
        for (int ks = 0; ks < 16; ks++) qf[ks] = *(const bf16x8*)(qp + ks * 32);
    }

    f32x4 acc[32];
#pragma unroll
    for (int i = 0; i < 32; i++) acc[i] = zero4();
    float m[4] = {-1e30f, -1e30f, -1e30f, -1e30f};
    float lsum[4] = {0.f, 0.f, 0.f, 0.f};
    const float scale = 0.04419417382415922f;  // 1/sqrt(512)
    int kvbeg = s * KVCH;

    // stage 32KB K tile: 32 segs of 1KB; 8 waves x 4 segs; LDS linear per lane
    auto STAGE = [&](int buf, int kv0) {
#pragma unroll
        for (int i = 0; i < 4; i++) {
            int seg = wave * 4 + i;
            gll16(Kg + (size_t)(kv0 + (seg & 1) * 16 + l15) * LDQ +
                      (seg >> 1) * 32 + lg * 8,
                  Klds + buf * 16384 + seg * 512 + lane * 8);
        }
    };

    STAGE(0, kvbeg);
    asm volatile("s_waitcnt vmcnt(0)" ::: "memory");
    __syncthreads();

    for (int t = 0; t < KVCH / KVB; ++t) {
        int kv0 = kvbeg + t * KVB;
        int buf = t & 1;
        if (t + 1 < KVCH / KVB) STAGE(buf ^ 1, kv0 + KVB);
        const u16* kb = Klds + buf * 16384;

        // ---- S = Q(16x512) @ K^T(512x32) ----
        f32x4 sf[2];
        sf[0] = zero4(); sf[1] = zero4();
        __builtin_amdgcn_s_setprio(1);
#pragma unroll
        for (int ks = 0; ks < 16; ks++) {
            bf16x8 b0 = *(const bf16x8*)(kb + ks * 1024 + lane * 8);
            bf16x8 b1 = *(const bf16x8*)(kb + ks * 1024 + 512 + lane * 8);
            sf[0] = __builtin_amdgcn_mfma_f32_16x16x32_bf16(qf[ks], b0, sf[0], 0, 0, 0);
            sf[1] = __builtin_amdgcn_mfma_f32_16x16x32_bf16(qf[ks], b1, sf[1], 0, 0, 0);
        }
        __builtin_amdgcn_s_setprio(0);

        // ---- mask + online softmax (defer-max THR=8) ----
        u32 w0[4];
#pragma unroll
        for (int r = 0; r < 4; r++)
            w0[r] = bits[(size_t)(qbase + lg * 4 + r) * 256 + (kv0 >> 5)];
        float pvv[2][4];
        float mx[4] = {-1e30f, -1e30f, -1e30f, -1e30f};
#pragma unroll
        for (int f = 0; f < 2; f++) {
            int c = f * 16 + l15;
#pragma unroll
            for (int r = 0; r < 4; r++) {
                bool bit = (w0[r] >> c) & 1u;
                float sv = bit ? sf[f][r] * scale : -1e30f;
                pvv[f][r] = sv;
                mx[r] = fmaxf(mx[r], sv);
            }
        }
#pragma unroll
        for (int r = 0; r < 4; r++) {
#pragma unroll
            for (int off = 8; off; off >>= 1)
                mx[r] = fmaxf(mx[r], __shfl_xor(mx[r], off, 64));
        }
        bool need = false;
#pragma unroll
        for (int r = 0; r < 4; r++) need |= (mx[r] > m[r] + 8.0f);
        if (__any(need ? 1 : 0)) {
            float csc[4];
#pragma unroll
            for (int r = 0; r < 4; r++) {
                float mn = fmaxf(m[r], mx[r]);
                csc[r] = __expf(m[r] - mn);
                m[r] = mn;
                lsum[r] *= csc[r];
            }
#pragma unroll
            for (int i = 0; i < 32; i++) {
                f32x4 a = acc[i];
                a[0] *= csc[0]; a[1] *= csc[1]; a[2] *= csc[2]; a[3] *= csc[3];
                acc[i] = a;
            }
        }
#pragma unroll
        for (int f = 0; f < 2; f++)
#pragma unroll
            for (int r = 0; r < 4; r++)
                pvv[f][r] = (pvv[f][r] < -1e29f) ? 0.f : __expf(pvv[f][r] - m[r]);
#pragma unroll
        for (int r = 0; r < 4; r++) {
            float rs = pvv[0][r] + pvv[1][r];
#pragma unroll
            for (int off = 8; off; off >>= 1) rs += __shfl_xor(rs, off, 64);
            lsum[r] += rs;
        }

        // ---- P (D-layout) -> per-wave LDS (linear layout) -> A-frag ----
        // P[row][col] at u16 idx (col>>3)*128 + row*8 + (col&7)
#pragma unroll
        for (int f = 0; f < 2; f++)
#pragma unroll
            for (int r = 0; r < 4; r++)
                myp[(f * 2 + (l15 >> 3)) * 128 + (lg * 4 + r) * 8 + (l15 & 7)] = f2b(pvv[f][r]);
        asm volatile("s_waitcnt lgkmcnt(0)" ::: "memory");
        __builtin_amdgcn_sched_barrier(0);
        bf16x8 pa = *(const bf16x8*)(myp + lane * 8);

        // ---- O += P(16x32) @ V(32x512), V from tiled-VT (L1), prefetch 4 ----
        const u16* vb = VTt + (size_t)(kv0 >> 5) * (HID * 32);
        bf16x8 vreg[4];
#pragma unroll
        for (int j = 0; j < 4; j++)
            vreg[j] = *(const bf16x8*)(vb + (size_t)(j * 16 + l15) * 32 + lg * 8);
        __builtin_amdgcn_s_setprio(1);
#pragma unroll
        for (int cf = 0; cf < 32; ++cf) {
            bf16x8 vn;
            if (cf + 4 < 32)
                vn = *(const bf16x8*)(vb + (size_t)((cf + 4) * 16 + l15) * 32 + lg * 8);
            acc[cf] = __builtin_amdgcn_mfma_f32_16x16x32_bf16(pa, vreg[cf & 3], acc[cf], 0, 0, 0);
            if (cf + 4 < 32) vreg[cf & 3] = vn;
        }
        __builtin_amdgcn_s_setprio(0);

        asm volatile("s_waitcnt vmcnt(0)" ::: "memory");
        __syncthreads();
    }

    // ---- write partials ----
    if (l15 == 0) {
#pragma unroll
        for (int r = 0; r < 4; r++) {
            size_t o = (size_t)s * NROW + qbase + lg * 4 + r;
            Mpart[o] = m[r];
            Lpart[o] = lsum[r];
        }
    }
#pragma unroll
    for (int cf = 0; cf < 32; cf++) {
        int col = cf * 16 + l15;
#pragma unroll
        for (int r = 0; r < 4; r++) {
            size_t row = (size_t)s * NROW + qbase + lg * 4 + r;
            Opart[row * HID + col] = f2b(acc[cf][r]);
        }
    }
}

// combine 4 split partials -> O16
__global__ __launch_bounds__(256) void attn_combine(const u16* __restrict__ Opart,
                                                    const float* __restrict__ Mpart,
                                                    const float* __restrict__ Lpart,
                                                    u16* __restrict__ O16) {
    int idx = blockIdx.x * 256 + threadIdx.x;
    int row = idx >> 6;
    int c8 = (idx & 63) << 3;
    float ms[NSPLIT], M = -1e30f;
#pragma unroll
    for (int s = 0; s < NSPLIT; s++) {
        ms[s] = Mpart[(size_t)s * NROW + row];
        M = fmaxf(M, ms[s]);
    }
    float w[NSPLIT], L = 0.f;
#pragma unroll
    for (int s = 0; s < NSPLIT; s++) {
        w[s] = __expf(ms[s] - M);
        L += Lpart[(size_t)s * NROW + row] * w[s];
    }
    float inv = 1.f / L;
    float o[8];
#pragma unroll
    for (int j = 0; j < 8; j++) o[j] = 0.f;
#pragma unroll
    for (int s = 0; s < NSPLIT; s++) {
        bf16x8 p = *(const bf16x8*)(Opart + ((size_t)s * NROW + row) * HID + c8);
#pragma unroll
        for (int j = 0; j < 8; j++) o[j] += (float)p[j] * w[s];
    }
    bf16x8 res;
#pragma unroll
    for (int j = 0; j < 8; j++) {
        u16 b = f2b(o[j] * inv);
        res[j] = *(bf16_t*)&b;
    }
    *(bf16x8*)(O16 + (size_t)row * HID + c8) = res;
}

// ---------------- layernorm(a) (residual pre-added in GEMM epilogue) ---------
__global__ __launch_bounds__(256) void ln_single(const float* __restrict__ a,
                                                 const float* __restrict__ g,
                                                 const float* __restrict__ be,
                                                 float* __restrict__ outF,
                                                 u16* __restrict__ outH) {
    int row = blockIdx.x, t = threadIdx.x;
    const float* ar = a + (size_t)row * HID;
    float x0 = ar[t];
    float x1 = ar[t + 256];
    float s = x0 + x1, s2 = x0 * x0 + x1 * x1;
#pragma unroll
    for (int off = 32; off; off >>= 1) {
        s += __shfl_xor(s, off, 64);
        s2 += __shfl_xor(s2, off, 64);
    }
    __shared__ float ls[4], ls2[4];
    int wv = t >> 6, ln = t & 63;
    if (ln == 0) { ls[wv] = s; ls2[wv] = s2; }
    __syncthreads();
    float S = ls[0] + ls[1] + ls[2] + ls[3];
    float S2 = ls2[0] + ls2[1] + ls2[2] + ls2[3];
    float mu = S * (1.f / 512.f);
    float var = S2 * (1.f / 512.f) - mu * mu;
    float inv = rsqrtf(var + 1e-5f);
    float y0 = (x0 - mu) * inv * g[t] + be[t];
    float y1 = (x1 - mu) * inv * g[t + 256] + be[t + 256];
    size_t o = (size_t)row * HID + t;
    if (outF) { outF[o] = y0; outF[o + 256] = y1; }
    if (outH) { outH[o] = f2b(y0); outH[o + 256] = f2b(y1); }
}

// ---------------- logits ----------------
__global__ __launch_bounds__(256) void logits_k(const u16* __restrict__ hfin,
                                                const float* __restrict__ Ws,
                                                const float* __restrict__ bs,
                                                float* __restrict__ out) {
    int row = blockIdx.x * 4 + (threadIdx.x >> 6);
    int lane = threadIdx.x & 63;
    const u16* hp = hfin + (size_t)row * HID + lane * 8;
    float sum = 0.f;
#pragma unroll
    for (int j = 0; j < 8; j++) sum += b2f(hp[j]) * Ws[lane * 8 + j];
#pragma unroll
    for (int off = 32; off; off >>= 1) sum += __shfl_xor(sum, off, 64);
    if (lane == 0) out[row] = sum + bs[0];
}

// ---------------- host launcher ----------------
extern "C" void kernel_launch(void* const* d_in, const int* in_sizes, int n_in,
                              void* d_out, int out_size, void* d_ws, size_t ws_size,
                              hipStream_t stream) {
    const float* x   = (const float*)d_in[0];
    const void*  adj = d_in[1];
    const float* Win = (const float*)d_in[2];
    const float* b_in= (const float*)d_in[3];
    const float* Wq  = (const float*)d_in[4];
    const float* bq  = (const float*)d_in[5];
    const float* Wk  = (const float*)d_in[6];
    const float* bk  = (const float*)d_in[7];
    const float* Wv  = (const float*)d_in[8];
    const float* bv  = (const float*)d_in[9];
    const float* Wo  = (const float*)d_in[10];
    const float* bo  = (const float*)d_in[11];
    const float* Ws  = (const float*)d_in[12];
    const float* bs  = (const float*)d_in[13];
    const float* g1  = (const float*)d_in[14];
    const float* be1 = (const float*)d_in[15];
    const float* g2  = (const float*)d_in[16];
    const float* be2 = (const float*)d_in[17];
    const float* Wf1 = (const float*)d_in[18];
    const float* bf1 = (const float*)d_in[19];
    const float* Wf2 = (const float*)d_in[20];
    const float* bf2 = (const float*)d_in[21];

    char* ws = (char*)d_ws;
    const size_t MB = 1u << 20;
    const size_t OFF_PART = 0;            // 32MB partial O (attn..combine) overlays:
    const size_t OFF_X16  = 0;            //   4MB x bf16   (dead after h-gemm)
    const size_t OFF_H16  = 4 * MB;       //   8MB h bf16   (dead after qkv-gemm)
    const size_t OFF_HN32 = 12 * MB;      //  16MB ln1 f32  (written after combine)
    const size_t OFF_HN16 = 28 * MB;      //   8MB ln1 bf16
    const size_t OFF_FF1  = 4 * MB;       //   8MB (overlays dead H16)
    const size_t OFF_HF32 = 36 * MB;      //  16MB h f32 (h-gemm .. o-proj epilogue)
    const size_t OFF_QKV  = 52 * MB;      //  24MB fused qkv bf16 (dead after attn)
    const size_t OFF_OP32 = 52 * MB;      //  16MB h+oproj f32 (overlays dead QKV)
    const size_t OFF_FF2  = 52 * MB;      //  16MB hn+ff2 (overlays dead OP32)
    const size_t OFF_VT   = 76 * MB;      //   8MB tiled VT (dead after attn)
    const size_t OFF_HFIN = 76 * MB;      //   8MB final hidden (overlays dead VT)
    const size_t OFF_H2   = 84 * MB;      //   8MB attn out bf16
    const size_t OFF_BITS = 92 * MB;      //   8MB adjacency bitmask
    size_t off = 100 * MB;
    const size_t OFF_WINT = off;  off += 262144;
    const size_t OFF_QKVT = off;  off += 1572864;
    const size_t OFF_WOT  = off;  off += 524288;
    const size_t OFF_WF1T = off;  off += 524288;
    const size_t OFF_WF2T = off;  off += 524288;
    const size_t OFF_BQKV = off;  off += 8192;
    const size_t OFF_MODE = off;  off += 4096;
    const size_t OFF_MPART= off;  off += 131072;
    const size_t OFF_LPART= off;  off += 131072;

    u16* pX16   = (u16*)(ws + OFF_X16);
    u16* pH16   = (u16*)(ws + OFF_H16);
    float* pHN32= (float*)(ws + OFF_HN32);
    u16* pHN16  = (u16*)(ws + OFF_HN16);
    u16* pFF1   = (u16*)(ws + OFF_FF1);
    float* pHF32= (float*)(ws + OFF_HF32);
    u16* pQKV   = (u16*)(ws + OFF_QKV);
    float* pOP32= (float*)(ws + OFF_OP32);
    float* pFF2 = (float*)(ws + OFF_FF2);
    u16* pVT    = (u16*)(ws + OFF_VT);
    u16* pHFIN  = (u16*)(ws + OFF_HFIN);
    u16* pH2    = (u16*)(ws + OFF_H2);
    u32* pBits  = (u32*)(ws + OFF_BITS);
    u16* pPart  = (u16*)(ws + OFF_PART);
    u16* pWinT  = (u16*)(ws + OFF_WINT);
    u16* pQKVT  = (u16*)(ws + OFF_QKVT);
    u16* pWoT   = (u16*)(ws + OFF_WOT);
    u16* pWf1T  = (u16*)(ws + OFF_WF1T);
    u16* pWf2T  = (u16*)(ws + OFF_WF2T);
    float* pBqkv= (float*)(ws + OFF_BQKV);
    int* pMode  = (int*)(ws + OFF_MODE);
    float* pMp  = (float*)(ws + OFF_MPART);
    float* pLp  = (float*)(ws + OFF_LPART);

    // adjacency bitmask
    sniff_adj<<<1, 256, 0, stream>>>((const u32*)adj, pMode);
    build_bits<<<NROW, 256, 0, stream>>>(adj, pMode, pBits);

    // conversions
    convert_f32_bf16<<<(NROW * DIN) / 256, 256, 0, stream>>>(x, pX16, NROW * DIN);
    transpose_wt<<<dim3(8, 4), 256, 0, stream>>>(Win, pWinT, DIN, HID);
    transpose_wt<<<dim3(8, 8), 256, 0, stream>>>(Wq, pQKVT, HID, HID);
    transpose_wt<<<dim3(8, 8), 256, 0, stream>>>(Wk, pQKVT + 512 * 512, HID, HID);
    transpose_wt<<<dim3(8, 8), 256, 0, stream>>>(Wv, pQKVT + 2 * 512 * 512, HID, HID);
    transpose_wt<<<dim3(8, 8), 256, 0, stream>>>(Wo, pWoT, HID, HID);
    transpose_wt<<<dim3(8, 8), 256, 0, stream>>>(Wf1, pWf1T, HID, HID);
    transpose_wt<<<dim3(8, 8), 256, 0, stream>>>(Wf2, pWf2T, HID, HID);
    concat_bias<<<6, 256, 0, stream>>>(bq, bk, bv, pBqkv);

    // h = x @ Win + b_in (f32 + bf16)
    gemm_k<<<dim3(8, 64), 256, 0, stream>>>(pX16, DIN, pWinT, b_in, nullptr,
                                            pHF32, pH16, HID, 0, DIN);
    // qkv = h @ [Wq|Wk|Wv] (bf16, fused, ldo=1536)
    gemm_k<<<dim3(24, 64), 256, 0, stream>>>(pH16, HID, pQKVT, pBqkv, nullptr,
                                             nullptr, pQKV, LDQ, 0, HID);
    // tiled vt
    transpose_v_tiled<<<dim3(HID / 64, NROW / 64), 256, 0, stream>>>(pQKV + 1024, LDQ, pVT);
    // attention (split-KV) + combine; LDS padded to 88KB -> exactly 1 block/CU
    attn_kernel<<<64 * NSPLIT, 512, 90112, stream>>>(pQKV, pVT, pBits, pPart, pMp, pLp);
    attn_combine<<<NROW * HID / (256 * 8), 256, 0, stream>>>(pPart, pMp, pLp, pH2);
    // o-proj (f32) with fused residual: OP32 = h + (h2 @ Wo + bo)
    gemm_k<<<dim3(8, 64), 256, 0, stream>>>(pH2, HID, pWoT, bo, pHF32,
                                            pOP32, nullptr, HID, 0, HID);
    // LN1
    ln_single<<<NROW, 256, 0, stream>>>(pOP32, g1, be1, pHN32, pHN16);
    // ff1 = relu(hn @ Wf1 + bf1)
    gemm_k<<<dim3(8, 64), 256, 0, stream>>>(pHN16, HID, pWf1T, bf1, nullptr,
                                            nullptr, pFF1, HID, 1, HID);
    // ff2 with fused residual: FF2 = hn + (ff1 @ Wf2 + bf2)
    gemm_k<<<dim3(8, 64), 256, 0, stream>>>(pFF1, HID, pWf2T, bf2, pHN32,
                                            pFF2, nullptr, HID, 0, HID);
    // LN2 -> bf16
    ln_single<<<NROW, 256, 0, stream>>>(pFF2, g2, be2, nullptr, pHFIN);
    // logits
    logits_k<<<NROW / 4, 256, 0, stream>>>(pHFIN, Ws, bs, (float*)d_out);
}